// Round 15
// baseline (181.631 us; speedup 1.0000x reference)
//
#include <hip/hip_runtime.h>
#include <math.h>

// GCNII graph convolution, N=50000, F=256, E=800000, f32 in/out.
// R15: H0 stream moved out of gather into gemm's A-fragment load
//      (init = (1-a)PH + a*H0 is linear -> defer combine). Gather writes
//      phb = bf16(PH) only: loses the 51MB H0 stream that competed with the
//      latency-critical random Hs gathers (R12: nt-hint on H0 alone = -3us).
//      gemm builds A = bf16((1-a)ph + a*h0) on the fly (VALU hides under
//      its memory streams). Rest = R14 (u8 CSR tables, identity-folded W).

#define F_DIM 256
#define CHUNK 20000

typedef __attribute__((ext_vector_type(4))) float f32x4;
typedef __attribute__((ext_vector_type(8))) short short8;
typedef __attribute__((ext_vector_type(4))) unsigned short u16x4;

static __device__ __forceinline__ unsigned short f2bf(float f) {
    unsigned int u = __float_as_uint(f);
    u += 0x7fffu + ((u >> 16) & 1u);
    return (unsigned short)(u >> 16);
}
static __device__ __forceinline__ float bf2f(unsigned short u) {
    return __uint_as_float((unsigned int)u << 16);
}

// ---- histogram: block = (chunk c, which). u8x4-packed LDS, all nodes ------

__global__ __launch_bounds__(1024) void hist_kernel(
        const int* __restrict__ src, const int* __restrict__ dst,
        unsigned* __restrict__ histS, unsigned* __restrict__ histD,
        unsigned char* __restrict__ lrank, int E, int wpc4) {
    __shared__ unsigned hist[12544];
    int b = blockIdx.x;
    int which = b & 1, c = b >> 1;
    int tid = threadIdx.x;
    int e0 = c * CHUNK;
    int e1 = e0 + CHUNK < E ? e0 + CHUNK : E;
    const int* eptr = which ? dst : src;
    unsigned* outh = which ? histD : histS;

    for (int w = tid; w < wpc4; w += 1024) hist[w] = 0;
    __syncthreads();
    for (int e = e0 + tid; e < e1; e += 1024) {
        int s = eptr[e];
        int sh = (s & 3) * 8;
        unsigned old = atomicAdd(&hist[s >> 2], 1u << sh);
        if (!which) lrank[e] = (unsigned char)((old >> sh) & 0xffu);
    }
    __syncthreads();
    for (int w = tid; w < wpc4; w += 1024)
        outh[(size_t)c * wpc4 + w] = hist[w];
}

// ---- histS/histD pass: cnt, dinv, u8-packed per-chunk bases, blk sums -----

__global__ __launch_bounds__(256) void sumbase_kernel(
        const unsigned* __restrict__ histS, const unsigned* __restrict__ histD,
        int* __restrict__ cnt, float* __restrict__ dinv,
        unsigned* __restrict__ baseL, int* __restrict__ blksum,
        int wpc4, int nchunk, int n) {
    int tid = threadIdx.x;
    int w = blockIdx.x * 256 + tid;
    unsigned s0 = 0, s1 = 0, s2 = 0, s3 = 0;
    unsigned d0 = 0, d1 = 0, d2 = 0, d3 = 0;
    if (w < wpc4) {
        for (int c = 0; c < nchunk; ++c) {
            unsigned vs = histS[(size_t)c * wpc4 + w];
            unsigned vd = histD[(size_t)c * wpc4 + w];
            baseL[(size_t)c * wpc4 + w] = s0 | (s1 << 8) | (s2 << 16) | (s3 << 24);
            s0 += vs & 0xffu; s1 += (vs >> 8) & 0xffu;
            s2 += (vs >> 16) & 0xffu; s3 += vs >> 24;
            d0 += vd & 0xffu; d1 += (vd >> 8) & 0xffu;
            d2 += (vd >> 16) & 0xffu; d3 += vd >> 24;
        }
        int i0 = 4 * w;
        unsigned sv[4] = {s0, s1, s2, s3};
        unsigned dv[4] = {d0, d1, d2, d3};
        for (int k = 0; k < 4; ++k) {
            if (i0 + k < n) {
                cnt[i0 + k] = (int)sv[k];
                dinv[i0 + k] = rsqrtf((float)dv[k] + 1.0f);
            }
        }
    }
    int contrib = (w < wpc4) ? (int)(s0 + s1 + s2 + s3) : 0;
    int lane = tid & 63, wid = tid >> 6;
    int v = contrib;
    for (int off = 32; off > 0; off >>= 1) v += __shfl_down(v, off, 64);
    if (lane == 0) blksum[4 * blockIdx.x + wid] = v;
}

// ---- row_ptr: per-block self-scan of blksum + local scan ------------------

__global__ __launch_bounds__(256) void rowptr_kernel(const int* __restrict__ cnt,
                                                     const int* __restrict__ blksum,
                                                     int* __restrict__ row_ptr,
                                                     int n, int nb) {
    int tid = threadIdx.x;
    int lane = tid & 63, w = tid >> 6;
    int bv = (tid < nb) ? blksum[tid] : 0;
    int bs = bv;
    for (int off = 1; off < 64; off <<= 1) {
        int t = __shfl_up(bv, off, 64);
        if (lane >= off) bv += t;
    }
    __shared__ int wsb[4];
    __shared__ int sbo[256];
    if (lane == 63) wsb[w] = bv;
    __syncthreads();
    if (tid == 0) {
        int run = 0;
        for (int k = 0; k < 4; ++k) { int t = wsb[k]; wsb[k] = run; run += t; }
    }
    __syncthreads();
    sbo[tid] = wsb[w] + bv - bs;
    __syncthreads();
    int blockoff = sbo[blockIdx.x];
    int i = blockIdx.x * 256 + tid;
    int s = (i < n) ? cnt[i] : 0;
    int v = s;
    for (int off = 1; off < 64; off <<= 1) {
        int t = __shfl_up(v, off, 64);
        if (lane >= off) v += t;
    }
    __shared__ int ws[4];
    if (lane == 63) ws[w] = v;
    __syncthreads();
    if (tid == 0) {
        int run = 0;
        for (int k = 0; k < 4; ++k) { int t = ws[k]; ws[k] = run; run += t; }
    }
    __syncthreads();
    if (i <= n) row_ptr[i] = blockoff + ws[w] + v - s;
}

// ---- merged: fill (atomic-free CSR col) + Hs build + Wt' build ------------

__global__ __launch_bounds__(256) void fillhswt_kernel(
        const int* __restrict__ src, const int* __restrict__ dst,
        const int* __restrict__ row_ptr, const unsigned char* __restrict__ baseL8,
        const unsigned char* __restrict__ lrank, int* __restrict__ col,
        const float* __restrict__ H, const float* __restrict__ dinv,
        unsigned short* __restrict__ Hs,
        const float* __restrict__ W, unsigned short* __restrict__ Wt,
        const float* __restrict__ lamda_p, const int* __restrict__ l_p,
        int E, int wpc4, int nfill, int total4) {
    int bid = blockIdx.x;
    int tid = threadIdx.x;
    if (bid < nfill) {
        int e = bid * 256 + tid;
        if (e < E) {
            int c = e / CHUNK;
            int s = src[e];
            unsigned lb = baseL8[(size_t)c * (4 * wpc4) + s];   // 2MB, L2-resident
            unsigned pos = (unsigned)row_ptr[s] + lb + lrank[e];
            col[pos] = dst[e];
        }
    } else {
        int i = (bid - nfill) * 256 + tid;   // f32x4 / u16x4 units
        if (i < total4) {
            int row = i >> 6;                 // 64 x f32x4 per row
            float d = dinv[row];
            f32x4 x = ((const f32x4*)H)[i];
            u16x4 o;
            o[0] = f2bf(x[0] * d); o[1] = f2bf(x[1] * d);
            o[2] = f2bf(x[2] * d); o[3] = f2bf(x[3] * d);
            ((u16x4*)Hs)[i] = o;
        } else {
            int t = i - total4;               // 0..65535 -> Wt' build
            if (t < F_DIM * F_DIM) {
                float beta = logf(lamda_p[0] / (float)l_p[0] + 1.0f);
                int nn = t >> 8, kk = t & 255;
                float v = beta * W[kk * F_DIM + nn];
                if (kk == nn) v += 1.0f - beta;
                Wt[nn * F_DIM + kk] = f2bf(v);
            }
        }
    }
}

// ---- gather: one wave per row, 512B bf16 loads, 8-deep edge unroll --------
// Writes phb = bf16(PH) only (nt store); H0 combine deferred to gemm.

#define ACC(A, h) { A[0] += bf2f(h[0]); A[1] += bf2f(h[1]); \
                    A[2] += bf2f(h[2]); A[3] += bf2f(h[3]); }

__global__ __launch_bounds__(256) void gather_kernel(
        const unsigned short* __restrict__ Hs,
        const int* __restrict__ row_ptr, const int* __restrict__ col,
        const float* __restrict__ dinv,
        unsigned short* __restrict__ phb, int n) {
    int wave = threadIdx.x >> 6;
    int lane = threadIdx.x & 63;
    int row = blockIdx.x * 4 + wave;
    if (row >= n) return;
    const u16x4* Hs4 = (const u16x4*)Hs;

    int beg = row_ptr[row], end = row_ptr[row + 1];
    f32x4 a0 = 0.0f, a1 = 0.0f, a2 = 0.0f, a3 = 0.0f;
    int e = beg;
    for (; e + 8 <= end; e += 8) {             // 8 gathers in flight
        int j0 = col[e+0], j1 = col[e+1], j2 = col[e+2], j3 = col[e+3];
        int j4 = col[e+4], j5 = col[e+5], j6 = col[e+6], j7 = col[e+7];
        u16x4 h0 = Hs4[j0*64+lane], h1 = Hs4[j1*64+lane];
        u16x4 h2 = Hs4[j2*64+lane], h3 = Hs4[j3*64+lane];
        u16x4 h4 = Hs4[j4*64+lane], h5 = Hs4[j5*64+lane];
        u16x4 h6 = Hs4[j6*64+lane], h7 = Hs4[j7*64+lane];
        ACC(a0, h0) ACC(a1, h1) ACC(a2, h2) ACC(a3, h3)
        ACC(a0, h4) ACC(a1, h5) ACC(a2, h6) ACC(a3, h7)
    }
    for (; e + 4 <= end; e += 4) {
        int j0 = col[e+0], j1 = col[e+1], j2 = col[e+2], j3 = col[e+3];
        u16x4 h0 = Hs4[j0*64+lane], h1 = Hs4[j1*64+lane];
        u16x4 h2 = Hs4[j2*64+lane], h3 = Hs4[j3*64+lane];
        ACC(a0, h0) ACC(a1, h1) ACC(a2, h2) ACC(a3, h3)
    }
    for (; e < end; ++e) {
        int j = col[e];
        u16x4 h = Hs4[j*64+lane];
        ACC(a0, h)
    }
    // self loop: H/deg = Hs * dinv  =>  PH = dinv[row] * (sum + Hs_row)
    u16x4 hr = Hs4[row*64+lane];
    ACC(a2, hr)
    f32x4 acc = (a0 + a1) + (a2 + a3);
    float di = dinv[row];
    f32x4 ph = di * acc;
    u16x4 o;
    o[0] = f2bf(ph[0]); o[1] = f2bf(ph[1]);
    o[2] = f2bf(ph[2]); o[3] = f2bf(ph[3]);
    __builtin_nontemporal_store(o, (u16x4*)phb + row * 64 + lane);
}

// ---- GEMM: out = [(1-a)phb + a*H0] @ Wt' (identity pre-folded) ------------
// A-fragment built on the fly from phb (bf16) + H0 (f32) -> bf16.
// 4 waves/block; block tile 64 rows x 256 cols; wave w owns cols [w*64,+64).

__global__ __launch_bounds__(256) void gemm_kernel(
        const unsigned short* __restrict__ phb, const float* __restrict__ H0,
        const unsigned short* __restrict__ Wt, float* __restrict__ out,
        const float* __restrict__ alpha_p, int M) {
    int w = threadIdx.x >> 6;
    int mr = blockIdx.x * 64;
    int nc = w * 64;
    int lane = threadIdx.x & 63;
    int lo = lane & 15, hi = lane >> 4;
    float alpha = alpha_p[0], oma = 1.0f - alpha;

    f32x4 acc[4][4] = {};
    for (int kk = 0; kk < 8; ++kk) {
        int kb = kk * 32 + hi * 8;
        short8 a[4], b[4];
        for (int am = 0; am < 4; ++am) {
            int row = mr + am * 16 + lo;
            if (row < M) {
                size_t base = (size_t)row * F_DIM + kb;
                short8 p = *(const short8*)(phb + base);
                f32x4 x0 = *(const f32x4*)(H0 + base);
                f32x4 x1 = *(const f32x4*)(H0 + base + 4);
                short8 t;
                t[0] = (short)f2bf(oma * bf2f((unsigned short)p[0]) + alpha * x0[0]);
                t[1] = (short)f2bf(oma * bf2f((unsigned short)p[1]) + alpha * x0[1]);
                t[2] = (short)f2bf(oma * bf2f((unsigned short)p[2]) + alpha * x0[2]);
                t[3] = (short)f2bf(oma * bf2f((unsigned short)p[3]) + alpha * x0[3]);
                t[4] = (short)f2bf(oma * bf2f((unsigned short)p[4]) + alpha * x1[0]);
                t[5] = (short)f2bf(oma * bf2f((unsigned short)p[5]) + alpha * x1[1]);
                t[6] = (short)f2bf(oma * bf2f((unsigned short)p[6]) + alpha * x1[2]);
                t[7] = (short)f2bf(oma * bf2f((unsigned short)p[7]) + alpha * x1[3]);
                a[am] = t;
            } else {
                a[am] = (short8)0;
            }
        }
        for (int bn = 0; bn < 4; ++bn) {
            int cb = nc + bn * 16 + lo;
            b[bn] = *(const short8*)(Wt + cb * F_DIM + kb);
        }
        for (int am = 0; am < 4; ++am)
            for (int bn = 0; bn < 4; ++bn)
                acc[am][bn] = __builtin_amdgcn_mfma_f32_16x16x32_bf16(
                    a[am], b[bn], acc[am][bn], 0, 0, 0);
    }

    // C/D layout: col = lane&15, row = (lane>>4)*4 + reg   [m89-verified]
    for (int am = 0; am < 4; ++am) {
        int rbase = mr + am * 16 + hi * 4;
        for (int r = 0; r < 4; ++r) {
            int row = rbase + r;
            if (row >= M) continue;
            for (int bn = 0; bn < 4; ++bn) {
                int c2 = nc + bn * 16 + lo;
                out[(size_t)row * F_DIM + c2] = acc[am][bn][r];
            }
        }
    }
}

// ---- launch ---------------------------------------------------------------

extern "C" void kernel_launch(void* const* d_in, const int* in_sizes, int n_in,
                              void* d_out, int out_size, void* d_ws, size_t ws_size,
                              hipStream_t stream) {
    const float* H     = (const float*)d_in[0];
    const int*   ei    = (const int*)d_in[1];
    const float* H0    = (const float*)d_in[2];
    const float* W     = (const float*)d_in[3];
    const float* lamda = (const float*)d_in[4];
    const float* alpha = (const float*)d_in[5];
    const int*   lp    = (const int*)d_in[6];

    int n = in_sizes[0] / F_DIM;
    int E = in_sizes[1] / 2;
    const int* src = ei;
    const int* dst = ei + E;
    float* out = (float*)d_out;

    int wpc4 = (n + 3) / 4;                // u8x4 words covering all nodes (12500)
    int nchunk = (E + CHUNK - 1) / CHUNK;  // 40
    int nb = (n + 256) / 256;              // scan blocks covering 0..n (196)

    char* ws = (char*)d_ws;
    size_t off = 0;
    auto alloc = [&](size_t bytes) -> void* {
        void* p = ws + off;
        off += (bytes + 255) & ~(size_t)255;
        return p;
    };
    unsigned* histS = (unsigned*)alloc((size_t)nchunk * wpc4 * 4);  // 2 MB
    unsigned* histD = (unsigned*)alloc((size_t)nchunk * wpc4 * 4);  // 2 MB
    unsigned* baseL = (unsigned*)alloc((size_t)nchunk * wpc4 * 4);  // 2 MB (u8)
    unsigned char* lrank = (unsigned char*)alloc((size_t)E);        // 0.8 MB
    int* cnt     = (int*)alloc((size_t)n * 4);
    int* row_ptr = (int*)alloc(((size_t)n + 1) * 4);
    int* blksum  = (int*)alloc((size_t)(nb + 8) * 4);
    float* dinv  = (float*)alloc((size_t)n * 4);
    int* colb    = (int*)alloc((size_t)E * 4);
    unsigned short* Wt  = (unsigned short*)alloc((size_t)F_DIM * F_DIM * 2);
    unsigned short* Hs  = (unsigned short*)alloc((size_t)n * F_DIM * 2);
    unsigned short* phb = (unsigned short*)alloc(((size_t)n + 64) * F_DIM * 2);

    hist_kernel<<<nchunk * 2, 1024, 0, stream>>>(src, dst, histS, histD, lrank,
                                                 E, wpc4);
    int wgrid = (wpc4 + 255) / 256;        // 49 blocks -> 196 blksum entries
    sumbase_kernel<<<wgrid, 256, 0, stream>>>(histS, histD, cnt, dinv, baseL,
                                              blksum, wpc4, nchunk, n);
    rowptr_kernel<<<nb, 256, 0, stream>>>(cnt, blksum, row_ptr, n, nb);
    int nfill = (E + 255) / 256;
    int total4 = n * 64;
    int nhswt = (total4 + F_DIM * F_DIM + 255) / 256;
    fillhswt_kernel<<<nfill + nhswt, 256, 0, stream>>>(
        src, dst, row_ptr, (const unsigned char*)baseL, lrank, colb,
        H, dinv, Hs, W, Wt, lamda, lp, E, wpc4, nfill, total4);
    gather_kernel<<<(n + 3) / 4, 256, 0, stream>>>(Hs, row_ptr, colb, dinv,
                                                   phb, n);
    int mtiles = (n + 63) / 64;
    gemm_kernel<<<mtiles, 256, 0, stream>>>(phb, H0, Wt, out, alpha, n);
}

// Round 16
// 162.902 us; speedup vs baseline: 1.1150x; 1.1150x over previous
//
#include <hip/hip_runtime.h>
#include <math.h>

// GCNII graph convolution, N=50000, F=256, E=800000, f32 in/out.
// R16: best-known combo from R11/R13/R15 bracketing:
//      - combine (1-a)PH + a*H0 IN GATHER (R15's gemm-side combine: 70us
//        latency-bound disaster, reverted);
//      - nt LOAD on H0 only (measured -2-3us on gather, R12/R13);
//      - PLAIN irb store (nt store evicted gemm's A from L2: +6us, R13);
//      - R14 u8 CSR tables + identity-folded Wt' + pure-MFMA gemm.

#define F_DIM 256
#define CHUNK 20000

typedef __attribute__((ext_vector_type(4))) float f32x4;
typedef __attribute__((ext_vector_type(8))) short short8;
typedef __attribute__((ext_vector_type(4))) unsigned short u16x4;

static __device__ __forceinline__ unsigned short f2bf(float f) {
    unsigned int u = __float_as_uint(f);
    u += 0x7fffu + ((u >> 16) & 1u);
    return (unsigned short)(u >> 16);
}
static __device__ __forceinline__ float bf2f(unsigned short u) {
    return __uint_as_float((unsigned int)u << 16);
}

// ---- histogram: block = (chunk c, which). u8x4-packed LDS, all nodes ------

__global__ __launch_bounds__(1024) void hist_kernel(
        const int* __restrict__ src, const int* __restrict__ dst,
        unsigned* __restrict__ histS, unsigned* __restrict__ histD,
        unsigned char* __restrict__ lrank, int E, int wpc4) {
    __shared__ unsigned hist[12544];
    int b = blockIdx.x;
    int which = b & 1, c = b >> 1;
    int tid = threadIdx.x;
    int e0 = c * CHUNK;
    int e1 = e0 + CHUNK < E ? e0 + CHUNK : E;
    const int* eptr = which ? dst : src;
    unsigned* outh = which ? histD : histS;

    for (int w = tid; w < wpc4; w += 1024) hist[w] = 0;
    __syncthreads();
    for (int e = e0 + tid; e < e1; e += 1024) {
        int s = eptr[e];
        int sh = (s & 3) * 8;
        unsigned old = atomicAdd(&hist[s >> 2], 1u << sh);
        if (!which) lrank[e] = (unsigned char)((old >> sh) & 0xffu);
    }
    __syncthreads();
    for (int w = tid; w < wpc4; w += 1024)
        outh[(size_t)c * wpc4 + w] = hist[w];
}

// ---- histS/histD pass: cnt, dinv, u8-packed per-chunk bases, blk sums -----

__global__ __launch_bounds__(256) void sumbase_kernel(
        const unsigned* __restrict__ histS, const unsigned* __restrict__ histD,
        int* __restrict__ cnt, float* __restrict__ dinv,
        unsigned* __restrict__ baseL, int* __restrict__ blksum,
        int wpc4, int nchunk, int n) {
    int tid = threadIdx.x;
    int w = blockIdx.x * 256 + tid;
    unsigned s0 = 0, s1 = 0, s2 = 0, s3 = 0;
    unsigned d0 = 0, d1 = 0, d2 = 0, d3 = 0;
    if (w < wpc4) {
        for (int c = 0; c < nchunk; ++c) {
            unsigned vs = histS[(size_t)c * wpc4 + w];
            unsigned vd = histD[(size_t)c * wpc4 + w];
            baseL[(size_t)c * wpc4 + w] = s0 | (s1 << 8) | (s2 << 16) | (s3 << 24);
            s0 += vs & 0xffu; s1 += (vs >> 8) & 0xffu;
            s2 += (vs >> 16) & 0xffu; s3 += vs >> 24;
            d0 += vd & 0xffu; d1 += (vd >> 8) & 0xffu;
            d2 += (vd >> 16) & 0xffu; d3 += vd >> 24;
        }
        int i0 = 4 * w;
        unsigned sv[4] = {s0, s1, s2, s3};
        unsigned dv[4] = {d0, d1, d2, d3};
        for (int k = 0; k < 4; ++k) {
            if (i0 + k < n) {
                cnt[i0 + k] = (int)sv[k];
                dinv[i0 + k] = rsqrtf((float)dv[k] + 1.0f);
            }
        }
    }
    int contrib = (w < wpc4) ? (int)(s0 + s1 + s2 + s3) : 0;
    int lane = tid & 63, wid = tid >> 6;
    int v = contrib;
    for (int off = 32; off > 0; off >>= 1) v += __shfl_down(v, off, 64);
    if (lane == 0) blksum[4 * blockIdx.x + wid] = v;
}

// ---- row_ptr: per-block self-scan of blksum + local scan ------------------

__global__ __launch_bounds__(256) void rowptr_kernel(const int* __restrict__ cnt,
                                                     const int* __restrict__ blksum,
                                                     int* __restrict__ row_ptr,
                                                     int n, int nb) {
    int tid = threadIdx.x;
    int lane = tid & 63, w = tid >> 6;
    int bv = (tid < nb) ? blksum[tid] : 0;
    int bs = bv;
    for (int off = 1; off < 64; off <<= 1) {
        int t = __shfl_up(bv, off, 64);
        if (lane >= off) bv += t;
    }
    __shared__ int wsb[4];
    __shared__ int sbo[256];
    if (lane == 63) wsb[w] = bv;
    __syncthreads();
    if (tid == 0) {
        int run = 0;
        for (int k = 0; k < 4; ++k) { int t = wsb[k]; wsb[k] = run; run += t; }
    }
    __syncthreads();
    sbo[tid] = wsb[w] + bv - bs;
    __syncthreads();
    int blockoff = sbo[blockIdx.x];
    int i = blockIdx.x * 256 + tid;
    int s = (i < n) ? cnt[i] : 0;
    int v = s;
    for (int off = 1; off < 64; off <<= 1) {
        int t = __shfl_up(v, off, 64);
        if (lane >= off) v += t;
    }
    __shared__ int ws[4];
    if (lane == 63) ws[w] = v;
    __syncthreads();
    if (tid == 0) {
        int run = 0;
        for (int k = 0; k < 4; ++k) { int t = ws[k]; ws[k] = run; run += t; }
    }
    __syncthreads();
    if (i <= n) row_ptr[i] = blockoff + ws[w] + v - s;
}

// ---- merged: fill (atomic-free CSR col) + Hs build + Wt' build ------------

__global__ __launch_bounds__(256) void fillhswt_kernel(
        const int* __restrict__ src, const int* __restrict__ dst,
        const int* __restrict__ row_ptr, const unsigned char* __restrict__ baseL8,
        const unsigned char* __restrict__ lrank, int* __restrict__ col,
        const float* __restrict__ H, const float* __restrict__ dinv,
        unsigned short* __restrict__ Hs,
        const float* __restrict__ W, unsigned short* __restrict__ Wt,
        const float* __restrict__ lamda_p, const int* __restrict__ l_p,
        int E, int wpc4, int nfill, int total4) {
    int bid = blockIdx.x;
    int tid = threadIdx.x;
    if (bid < nfill) {
        int e = bid * 256 + tid;
        if (e < E) {
            int c = e / CHUNK;
            int s = src[e];
            unsigned lb = baseL8[(size_t)c * (4 * wpc4) + s];   // 2MB, L2-resident
            unsigned pos = (unsigned)row_ptr[s] + lb + lrank[e];
            col[pos] = dst[e];
        }
    } else {
        int i = (bid - nfill) * 256 + tid;   // f32x4 / u16x4 units
        if (i < total4) {
            int row = i >> 6;                 // 64 x f32x4 per row
            float d = dinv[row];
            f32x4 x = ((const f32x4*)H)[i];
            u16x4 o;
            o[0] = f2bf(x[0] * d); o[1] = f2bf(x[1] * d);
            o[2] = f2bf(x[2] * d); o[3] = f2bf(x[3] * d);
            ((u16x4*)Hs)[i] = o;
        } else {
            int t = i - total4;               // 0..65535 -> Wt' build
            if (t < F_DIM * F_DIM) {
                float beta = logf(lamda_p[0] / (float)l_p[0] + 1.0f);
                int nn = t >> 8, kk = t & 255;
                float v = beta * W[kk * F_DIM + nn];
                if (kk == nn) v += 1.0f - beta;
                Wt[nn * F_DIM + kk] = f2bf(v);
            }
        }
    }
}

// ---- gather: one wave per row, 512B bf16 loads, 8-deep edge unroll --------
// nt LOAD on H0 (stream, keep L2 for Hs); PLAIN store irb (gemm reads it).

#define ACC(A, h) { A[0] += bf2f(h[0]); A[1] += bf2f(h[1]); \
                    A[2] += bf2f(h[2]); A[3] += bf2f(h[3]); }

__global__ __launch_bounds__(256) void gather_kernel(
        const unsigned short* __restrict__ Hs, const float* __restrict__ H0,
        const int* __restrict__ row_ptr, const int* __restrict__ col,
        const float* __restrict__ dinv, const float* __restrict__ alpha_p,
        unsigned short* __restrict__ irb, int n) {
    int wave = threadIdx.x >> 6;
    int lane = threadIdx.x & 63;
    int row = blockIdx.x * 4 + wave;
    if (row >= n) return;
    float alpha = alpha_p[0];
    const u16x4* Hs4 = (const u16x4*)Hs;

    int beg = row_ptr[row], end = row_ptr[row + 1];
    f32x4 a0 = 0.0f, a1 = 0.0f, a2 = 0.0f, a3 = 0.0f;
    int e = beg;
    for (; e + 8 <= end; e += 8) {             // 8 gathers in flight
        int j0 = col[e+0], j1 = col[e+1], j2 = col[e+2], j3 = col[e+3];
        int j4 = col[e+4], j5 = col[e+5], j6 = col[e+6], j7 = col[e+7];
        u16x4 h0 = Hs4[j0*64+lane], h1 = Hs4[j1*64+lane];
        u16x4 h2 = Hs4[j2*64+lane], h3 = Hs4[j3*64+lane];
        u16x4 h4 = Hs4[j4*64+lane], h5 = Hs4[j5*64+lane];
        u16x4 h6 = Hs4[j6*64+lane], h7 = Hs4[j7*64+lane];
        ACC(a0, h0) ACC(a1, h1) ACC(a2, h2) ACC(a3, h3)
        ACC(a0, h4) ACC(a1, h5) ACC(a2, h6) ACC(a3, h7)
    }
    for (; e + 4 <= end; e += 4) {
        int j0 = col[e+0], j1 = col[e+1], j2 = col[e+2], j3 = col[e+3];
        u16x4 h0 = Hs4[j0*64+lane], h1 = Hs4[j1*64+lane];
        u16x4 h2 = Hs4[j2*64+lane], h3 = Hs4[j3*64+lane];
        ACC(a0, h0) ACC(a1, h1) ACC(a2, h2) ACC(a3, h3)
    }
    for (; e < end; ++e) {
        int j = col[e];
        u16x4 h = Hs4[j*64+lane];
        ACC(a0, h)
    }
    // self loop: H/deg = Hs * dinv  =>  PH = dinv[row] * (sum + Hs_row)
    u16x4 hr = Hs4[row*64+lane];
    ACC(a2, hr)
    f32x4 acc = (a0 + a1) + (a2 + a3);
    float di = dinv[row];
    f32x4 h0v = __builtin_nontemporal_load((const f32x4*)H0 + row * 64 + lane);
    f32x4 init = (1.0f - alpha) * (di * acc) + alpha * h0v;
    u16x4 o;
    o[0] = f2bf(init[0]); o[1] = f2bf(init[1]);
    o[2] = f2bf(init[2]); o[3] = f2bf(init[3]);
    ((u16x4*)irb)[row * 64 + lane] = o;
}

// ---- GEMM: out = irb @ Wt' (identity pre-folded), pure MFMA + store -------
// 4 waves/block; block tile 64 rows x 256 cols; wave w owns cols [w*64,+64).

__global__ __launch_bounds__(256) void gemm_kernel(
        const unsigned short* __restrict__ irb, const unsigned short* __restrict__ Wt,
        float* __restrict__ out, int M) {
    int w = threadIdx.x >> 6;
    int mr = blockIdx.x * 64;
    int nc = w * 64;
    int lane = threadIdx.x & 63;
    int lo = lane & 15, hi = lane >> 4;

    f32x4 acc[4][4] = {};
    for (int kk = 0; kk < 8; ++kk) {
        int kb = kk * 32 + hi * 8;
        short8 a[4], b[4];
        for (int am = 0; am < 4; ++am) {
            int row = mr + am * 16 + lo;
            a[am] = (row < M) ? *(const short8*)(irb + (size_t)row * F_DIM + kb)
                              : (short8)0;
        }
        for (int bn = 0; bn < 4; ++bn) {
            int cb = nc + bn * 16 + lo;
            b[bn] = *(const short8*)(Wt + cb * F_DIM + kb);
        }
        for (int am = 0; am < 4; ++am)
            for (int bn = 0; bn < 4; ++bn)
                acc[am][bn] = __builtin_amdgcn_mfma_f32_16x16x32_bf16(
                    a[am], b[bn], acc[am][bn], 0, 0, 0);
    }

    // C/D layout: col = lane&15, row = (lane>>4)*4 + reg   [m89-verified]
    for (int am = 0; am < 4; ++am) {
        int rbase = mr + am * 16 + hi * 4;
        for (int r = 0; r < 4; ++r) {
            int row = rbase + r;
            if (row >= M) continue;
            for (int bn = 0; bn < 4; ++bn) {
                int c2 = nc + bn * 16 + lo;
                out[(size_t)row * F_DIM + c2] = acc[am][bn][r];
            }
        }
    }
}

// ---- launch ---------------------------------------------------------------

extern "C" void kernel_launch(void* const* d_in, const int* in_sizes, int n_in,
                              void* d_out, int out_size, void* d_ws, size_t ws_size,
                              hipStream_t stream) {
    const float* H     = (const float*)d_in[0];
    const int*   ei    = (const int*)d_in[1];
    const float* H0    = (const float*)d_in[2];
    const float* W     = (const float*)d_in[3];
    const float* lamda = (const float*)d_in[4];
    const float* alpha = (const float*)d_in[5];
    const int*   lp    = (const int*)d_in[6];

    int n = in_sizes[0] / F_DIM;
    int E = in_sizes[1] / 2;
    const int* src = ei;
    const int* dst = ei + E;
    float* out = (float*)d_out;

    int wpc4 = (n + 3) / 4;                // u8x4 words covering all nodes (12500)
    int nchunk = (E + CHUNK - 1) / CHUNK;  // 40
    int nb = (n + 256) / 256;              // scan blocks covering 0..n (196)

    char* ws = (char*)d_ws;
    size_t off = 0;
    auto alloc = [&](size_t bytes) -> void* {
        void* p = ws + off;
        off += (bytes + 255) & ~(size_t)255;
        return p;
    };
    unsigned* histS = (unsigned*)alloc((size_t)nchunk * wpc4 * 4);  // 2 MB
    unsigned* histD = (unsigned*)alloc((size_t)nchunk * wpc4 * 4);  // 2 MB
    unsigned* baseL = (unsigned*)alloc((size_t)nchunk * wpc4 * 4);  // 2 MB (u8)
    unsigned char* lrank = (unsigned char*)alloc((size_t)E);        // 0.8 MB
    int* cnt     = (int*)alloc((size_t)n * 4);
    int* row_ptr = (int*)alloc(((size_t)n + 1) * 4);
    int* blksum  = (int*)alloc((size_t)(nb + 8) * 4);
    float* dinv  = (float*)alloc((size_t)n * 4);
    int* colb    = (int*)alloc((size_t)E * 4);
    unsigned short* Wt  = (unsigned short*)alloc((size_t)F_DIM * F_DIM * 2);
    unsigned short* Hs  = (unsigned short*)alloc((size_t)n * F_DIM * 2);
    unsigned short* irb = (unsigned short*)alloc(((size_t)n + 64) * F_DIM * 2);

    hist_kernel<<<nchunk * 2, 1024, 0, stream>>>(src, dst, histS, histD, lrank,
                                                 E, wpc4);
    int wgrid = (wpc4 + 255) / 256;        // 49 blocks -> 196 blksum entries
    sumbase_kernel<<<wgrid, 256, 0, stream>>>(histS, histD, cnt, dinv, baseL,
                                              blksum, wpc4, nchunk, n);
    rowptr_kernel<<<nb, 256, 0, stream>>>(cnt, blksum, row_ptr, n, nb);
    int nfill = (E + 255) / 256;
    int total4 = n * 64;
    int nhswt = (total4 + F_DIM * F_DIM + 255) / 256;
    fillhswt_kernel<<<nfill + nhswt, 256, 0, stream>>>(
        src, dst, row_ptr, (const unsigned char*)baseL, lrank, colb,
        H, dinv, Hs, W, Wt, lamda, lp, E, wpc4, nfill, total4);
    gather_kernel<<<(n + 3) / 4, 256, 0, stream>>>(Hs, H0, row_ptr, colb, dinv,
                                                   alpha, irb, n);
    int mtiles = (n + 63) / 64;
    gemm_kernel<<<mtiles, 256, 0, stream>>>(irb, Wt, out, n);
}

// Round 17
// 159.298 us; speedup vs baseline: 1.1402x; 1.0226x over previous
//
#include <hip/hip_runtime.h>
#include <math.h>

// GCNII graph convolution, N=50000, F=256, E=800000, f32 in/out.
// R17: H0 moved out of gather (retry of R15 with a CORRECT gemm): gather
//      writes phb = bf16(PH) only (loses the 51MB H0 stream; fabric-bound
//      at 3.4TB/s -> -15us). gemm stages combined A = bf16((1-a)ph + a*h0)
//      through LDS: phase 1 fully-coalesced phb+H0 streams -> 64x264 bf16
//      tile (2-way bank alias = free), one barrier, phase 2 standard MFMA.
//      R15's mistake was per-fragment scattered A-build (latency-bound).
//      Rest = R16 (u8 CSR tables, identity-folded Wt', nt H0... n/a now).

#define F_DIM 256
#define CHUNK 20000

typedef __attribute__((ext_vector_type(4))) float f32x4;
typedef __attribute__((ext_vector_type(8))) short short8;
typedef __attribute__((ext_vector_type(4))) unsigned short u16x4;

static __device__ __forceinline__ unsigned short f2bf(float f) {
    unsigned int u = __float_as_uint(f);
    u += 0x7fffu + ((u >> 16) & 1u);
    return (unsigned short)(u >> 16);
}
static __device__ __forceinline__ float bf2f(unsigned short u) {
    return __uint_as_float((unsigned int)u << 16);
}

// ---- histogram: block = (chunk c, which). u8x4-packed LDS, all nodes ------

__global__ __launch_bounds__(1024) void hist_kernel(
        const int* __restrict__ src, const int* __restrict__ dst,
        unsigned* __restrict__ histS, unsigned* __restrict__ histD,
        unsigned char* __restrict__ lrank, int E, int wpc4) {
    __shared__ unsigned hist[12544];
    int b = blockIdx.x;
    int which = b & 1, c = b >> 1;
    int tid = threadIdx.x;
    int e0 = c * CHUNK;
    int e1 = e0 + CHUNK < E ? e0 + CHUNK : E;
    const int* eptr = which ? dst : src;
    unsigned* outh = which ? histD : histS;

    for (int w = tid; w < wpc4; w += 1024) hist[w] = 0;
    __syncthreads();
    for (int e = e0 + tid; e < e1; e += 1024) {
        int s = eptr[e];
        int sh = (s & 3) * 8;
        unsigned old = atomicAdd(&hist[s >> 2], 1u << sh);
        if (!which) lrank[e] = (unsigned char)((old >> sh) & 0xffu);
    }
    __syncthreads();
    for (int w = tid; w < wpc4; w += 1024)
        outh[(size_t)c * wpc4 + w] = hist[w];
}

// ---- histS/histD pass: cnt, dinv, u8-packed per-chunk bases, blk sums -----

__global__ __launch_bounds__(256) void sumbase_kernel(
        const unsigned* __restrict__ histS, const unsigned* __restrict__ histD,
        int* __restrict__ cnt, float* __restrict__ dinv,
        unsigned* __restrict__ baseL, int* __restrict__ blksum,
        int wpc4, int nchunk, int n) {
    int tid = threadIdx.x;
    int w = blockIdx.x * 256 + tid;
    unsigned s0 = 0, s1 = 0, s2 = 0, s3 = 0;
    unsigned d0 = 0, d1 = 0, d2 = 0, d3 = 0;
    if (w < wpc4) {
        for (int c = 0; c < nchunk; ++c) {
            unsigned vs = histS[(size_t)c * wpc4 + w];
            unsigned vd = histD[(size_t)c * wpc4 + w];
            baseL[(size_t)c * wpc4 + w] = s0 | (s1 << 8) | (s2 << 16) | (s3 << 24);
            s0 += vs & 0xffu; s1 += (vs >> 8) & 0xffu;
            s2 += (vs >> 16) & 0xffu; s3 += vs >> 24;
            d0 += vd & 0xffu; d1 += (vd >> 8) & 0xffu;
            d2 += (vd >> 16) & 0xffu; d3 += vd >> 24;
        }
        int i0 = 4 * w;
        unsigned sv[4] = {s0, s1, s2, s3};
        unsigned dv[4] = {d0, d1, d2, d3};
        for (int k = 0; k < 4; ++k) {
            if (i0 + k < n) {
                cnt[i0 + k] = (int)sv[k];
                dinv[i0 + k] = rsqrtf((float)dv[k] + 1.0f);
            }
        }
    }
    int contrib = (w < wpc4) ? (int)(s0 + s1 + s2 + s3) : 0;
    int lane = tid & 63, wid = tid >> 6;
    int v = contrib;
    for (int off = 32; off > 0; off >>= 1) v += __shfl_down(v, off, 64);
    if (lane == 0) blksum[4 * blockIdx.x + wid] = v;
}

// ---- row_ptr: per-block self-scan of blksum + local scan ------------------

__global__ __launch_bounds__(256) void rowptr_kernel(const int* __restrict__ cnt,
                                                     const int* __restrict__ blksum,
                                                     int* __restrict__ row_ptr,
                                                     int n, int nb) {
    int tid = threadIdx.x;
    int lane = tid & 63, w = tid >> 6;
    int bv = (tid < nb) ? blksum[tid] : 0;
    int bs = bv;
    for (int off = 1; off < 64; off <<= 1) {
        int t = __shfl_up(bv, off, 64);
        if (lane >= off) bv += t;
    }
    __shared__ int wsb[4];
    __shared__ int sbo[256];
    if (lane == 63) wsb[w] = bv;
    __syncthreads();
    if (tid == 0) {
        int run = 0;
        for (int k = 0; k < 4; ++k) { int t = wsb[k]; wsb[k] = run; run += t; }
    }
    __syncthreads();
    sbo[tid] = wsb[w] + bv - bs;
    __syncthreads();
    int blockoff = sbo[blockIdx.x];
    int i = blockIdx.x * 256 + tid;
    int s = (i < n) ? cnt[i] : 0;
    int v = s;
    for (int off = 1; off < 64; off <<= 1) {
        int t = __shfl_up(v, off, 64);
        if (lane >= off) v += t;
    }
    __shared__ int ws[4];
    if (lane == 63) ws[w] = v;
    __syncthreads();
    if (tid == 0) {
        int run = 0;
        for (int k = 0; k < 4; ++k) { int t = ws[k]; ws[k] = run; run += t; }
    }
    __syncthreads();
    if (i <= n) row_ptr[i] = blockoff + ws[w] + v - s;
}

// ---- merged: fill (atomic-free CSR col) + Hs build + Wt' build ------------

__global__ __launch_bounds__(256) void fillhswt_kernel(
        const int* __restrict__ src, const int* __restrict__ dst,
        const int* __restrict__ row_ptr, const unsigned char* __restrict__ baseL8,
        const unsigned char* __restrict__ lrank, int* __restrict__ col,
        const float* __restrict__ H, const float* __restrict__ dinv,
        unsigned short* __restrict__ Hs,
        const float* __restrict__ W, unsigned short* __restrict__ Wt,
        const float* __restrict__ lamda_p, const int* __restrict__ l_p,
        int E, int wpc4, int nfill, int total4) {
    int bid = blockIdx.x;
    int tid = threadIdx.x;
    if (bid < nfill) {
        int e = bid * 256 + tid;
        if (e < E) {
            int c = e / CHUNK;
            int s = src[e];
            unsigned lb = baseL8[(size_t)c * (4 * wpc4) + s];   // 2MB, L2-resident
            unsigned pos = (unsigned)row_ptr[s] + lb + lrank[e];
            col[pos] = dst[e];
        }
    } else {
        int i = (bid - nfill) * 256 + tid;   // f32x4 / u16x4 units
        if (i < total4) {
            int row = i >> 6;                 // 64 x f32x4 per row
            float d = dinv[row];
            f32x4 x = ((const f32x4*)H)[i];
            u16x4 o;
            o[0] = f2bf(x[0] * d); o[1] = f2bf(x[1] * d);
            o[2] = f2bf(x[2] * d); o[3] = f2bf(x[3] * d);
            ((u16x4*)Hs)[i] = o;
        } else {
            int t = i - total4;               // 0..65535 -> Wt' build
            if (t < F_DIM * F_DIM) {
                float beta = logf(lamda_p[0] / (float)l_p[0] + 1.0f);
                int nn = t >> 8, kk = t & 255;
                float v = beta * W[kk * F_DIM + nn];
                if (kk == nn) v += 1.0f - beta;
                Wt[nn * F_DIM + kk] = f2bf(v);
            }
        }
    }
}

// ---- gather: one wave per row, 512B bf16 loads, 8-deep edge unroll --------
// Writes phb = bf16(PH) only; H0 combine deferred to gemm phase 1.

#define ACC(A, h) { A[0] += bf2f(h[0]); A[1] += bf2f(h[1]); \
                    A[2] += bf2f(h[2]); A[3] += bf2f(h[3]); }

__global__ __launch_bounds__(256) void gather_kernel(
        const unsigned short* __restrict__ Hs,
        const int* __restrict__ row_ptr, const int* __restrict__ col,
        const float* __restrict__ dinv,
        unsigned short* __restrict__ phb, int n) {
    int wave = threadIdx.x >> 6;
    int lane = threadIdx.x & 63;
    int row = blockIdx.x * 4 + wave;
    if (row >= n) return;
    const u16x4* Hs4 = (const u16x4*)Hs;

    int beg = row_ptr[row], end = row_ptr[row + 1];
    f32x4 a0 = 0.0f, a1 = 0.0f, a2 = 0.0f, a3 = 0.0f;
    int e = beg;
    for (; e + 8 <= end; e += 8) {             // 8 gathers in flight
        int j0 = col[e+0], j1 = col[e+1], j2 = col[e+2], j3 = col[e+3];
        int j4 = col[e+4], j5 = col[e+5], j6 = col[e+6], j7 = col[e+7];
        u16x4 h0 = Hs4[j0*64+lane], h1 = Hs4[j1*64+lane];
        u16x4 h2 = Hs4[j2*64+lane], h3 = Hs4[j3*64+lane];
        u16x4 h4 = Hs4[j4*64+lane], h5 = Hs4[j5*64+lane];
        u16x4 h6 = Hs4[j6*64+lane], h7 = Hs4[j7*64+lane];
        ACC(a0, h0) ACC(a1, h1) ACC(a2, h2) ACC(a3, h3)
        ACC(a0, h4) ACC(a1, h5) ACC(a2, h6) ACC(a3, h7)
    }
    for (; e + 4 <= end; e += 4) {
        int j0 = col[e+0], j1 = col[e+1], j2 = col[e+2], j3 = col[e+3];
        u16x4 h0 = Hs4[j0*64+lane], h1 = Hs4[j1*64+lane];
        u16x4 h2 = Hs4[j2*64+lane], h3 = Hs4[j3*64+lane];
        ACC(a0, h0) ACC(a1, h1) ACC(a2, h2) ACC(a3, h3)
    }
    for (; e < end; ++e) {
        int j = col[e];
        u16x4 h = Hs4[j*64+lane];
        ACC(a0, h)
    }
    // self loop: H/deg = Hs * dinv  =>  PH = dinv[row] * (sum + Hs_row)
    u16x4 hr = Hs4[row*64+lane];
    ACC(a2, hr)
    f32x4 acc = (a0 + a1) + (a2 + a3);
    float di = dinv[row];
    f32x4 ph = di * acc;
    u16x4 o;
    o[0] = f2bf(ph[0]); o[1] = f2bf(ph[1]);
    o[2] = f2bf(ph[2]); o[3] = f2bf(ph[3]);
    ((u16x4*)phb)[row * 64 + lane] = o;
}

// ---- GEMM: out = [(1-a)phb + a*H0] @ Wt' (identity pre-folded) ------------
// Phase 1: coalesced phb+H0 streams -> combined bf16 A-tile in LDS
// (64 rows x 264 stride: 528B rows -> 2-way bank alias, free). One barrier.
// Phase 2: standard MFMA, A-fragments via ds_read_b128.

__global__ __launch_bounds__(256) void gemm_kernel(
        const unsigned short* __restrict__ phb, const float* __restrict__ H0,
        const unsigned short* __restrict__ Wt, float* __restrict__ out,
        const float* __restrict__ alpha_p, int M) {
    __shared__ __align__(16) unsigned short At[64][264];
    int tid = threadIdx.x;
    int mr = blockIdx.x * 64;
    float alpha = alpha_p[0], oma = 1.0f - alpha;

    // phase 1: 4096 u16x4-words (64 rows x 64 words), 16 iters x 256 thr
    for (int i = tid; i < 4096; i += 256) {
        int row = i >> 6, wc = i & 63;
        int grow = mr + row;
        u16x4 o;
        if (grow < M) {
            size_t base = (size_t)grow * F_DIM + wc * 4;
            u16x4 p = *(const u16x4*)(phb + base);
            f32x4 x = *(const f32x4*)(H0 + base);
            o[0] = f2bf(oma * bf2f(p[0]) + alpha * x[0]);
            o[1] = f2bf(oma * bf2f(p[1]) + alpha * x[1]);
            o[2] = f2bf(oma * bf2f(p[2]) + alpha * x[2]);
            o[3] = f2bf(oma * bf2f(p[3]) + alpha * x[3]);
        } else {
            o = (u16x4)0;
        }
        *(u16x4*)&At[row][wc * 4] = o;
    }
    __syncthreads();

    // phase 2: MFMA
    int w = tid >> 6;
    int nc = w * 64;
    int lane = tid & 63;
    int lo = lane & 15, hi = lane >> 4;

    f32x4 acc[4][4] = {};
    for (int kk = 0; kk < 8; ++kk) {
        int kb = kk * 32 + hi * 8;
        short8 a[4], b[4];
        for (int am = 0; am < 4; ++am)
            a[am] = *(const short8*)&At[am * 16 + lo][kb];
        for (int bn = 0; bn < 4; ++bn) {
            int cb = nc + bn * 16 + lo;
            b[bn] = *(const short8*)(Wt + cb * F_DIM + kb);
        }
        for (int am = 0; am < 4; ++am)
            for (int bn = 0; bn < 4; ++bn)
                acc[am][bn] = __builtin_amdgcn_mfma_f32_16x16x32_bf16(
                    a[am], b[bn], acc[am][bn], 0, 0, 0);
    }

    // C/D layout: col = lane&15, row = (lane>>4)*4 + reg   [m89-verified]
    for (int am = 0; am < 4; ++am) {
        int rbase = mr + am * 16 + hi * 4;
        for (int r = 0; r < 4; ++r) {
            int row = rbase + r;
            if (row >= M) continue;
            for (int bn = 0; bn < 4; ++bn) {
                int c2 = nc + bn * 16 + lo;
                out[(size_t)row * F_DIM + c2] = acc[am][bn][r];
            }
        }
    }
}

// ---- launch ---------------------------------------------------------------

extern "C" void kernel_launch(void* const* d_in, const int* in_sizes, int n_in,
                              void* d_out, int out_size, void* d_ws, size_t ws_size,
                              hipStream_t stream) {
    const float* H     = (const float*)d_in[0];
    const int*   ei    = (const int*)d_in[1];
    const float* H0    = (const float*)d_in[2];
    const float* W     = (const float*)d_in[3];
    const float* lamda = (const float*)d_in[4];
    const float* alpha = (const float*)d_in[5];
    const int*   lp    = (const int*)d_in[6];

    int n = in_sizes[0] / F_DIM;
    int E = in_sizes[1] / 2;
    const int* src = ei;
    const int* dst = ei + E;
    float* out = (float*)d_out;

    int wpc4 = (n + 3) / 4;                // u8x4 words covering all nodes (12500)
    int nchunk = (E + CHUNK - 1) / CHUNK;  // 40
    int nb = (n + 256) / 256;              // scan blocks covering 0..n (196)

    char* ws = (char*)d_ws;
    size_t off = 0;
    auto alloc = [&](size_t bytes) -> void* {
        void* p = ws + off;
        off += (bytes + 255) & ~(size_t)255;
        return p;
    };
    unsigned* histS = (unsigned*)alloc((size_t)nchunk * wpc4 * 4);  // 2 MB
    unsigned* histD = (unsigned*)alloc((size_t)nchunk * wpc4 * 4);  // 2 MB
    unsigned* baseL = (unsigned*)alloc((size_t)nchunk * wpc4 * 4);  // 2 MB (u8)
    unsigned char* lrank = (unsigned char*)alloc((size_t)E);        // 0.8 MB
    int* cnt     = (int*)alloc((size_t)n * 4);
    int* row_ptr = (int*)alloc(((size_t)n + 1) * 4);
    int* blksum  = (int*)alloc((size_t)(nb + 8) * 4);
    float* dinv  = (float*)alloc((size_t)n * 4);
    int* colb    = (int*)alloc((size_t)E * 4);
    unsigned short* Wt  = (unsigned short*)alloc((size_t)F_DIM * F_DIM * 2);
    unsigned short* Hs  = (unsigned short*)alloc((size_t)n * F_DIM * 2);
    unsigned short* phb = (unsigned short*)alloc(((size_t)n + 64) * F_DIM * 2);

    hist_kernel<<<nchunk * 2, 1024, 0, stream>>>(src, dst, histS, histD, lrank,
                                                 E, wpc4);
    int wgrid = (wpc4 + 255) / 256;        // 49 blocks -> 196 blksum entries
    sumbase_kernel<<<wgrid, 256, 0, stream>>>(histS, histD, cnt, dinv, baseL,
                                              blksum, wpc4, nchunk, n);
    rowptr_kernel<<<nb, 256, 0, stream>>>(cnt, blksum, row_ptr, n, nb);
    int nfill = (E + 255) / 256;
    int total4 = n * 64;
    int nhswt = (total4 + F_DIM * F_DIM + 255) / 256;
    fillhswt_kernel<<<nfill + nhswt, 256, 0, stream>>>(
        src, dst, row_ptr, (const unsigned char*)baseL, lrank, colb,
        H, dinv, Hs, W, Wt, lamda, lp, E, wpc4, nfill, total4);
    gather_kernel<<<(n + 3) / 4, 256, 0, stream>>>(Hs, row_ptr, colb, dinv,
                                                   phb, n);
    int mtiles = (n + 63) / 64;
    gemm_kernel<<<mtiles, 256, 0, stream>>>(phb, H0, Wt, out, alpha, n);
}